// Round 3
// baseline (667.201 us; speedup 1.0000x reference)
//
#include <hip/hip_runtime.h>
#include <hip/hip_bf16.h>
#include <hip/hip_fp16.h>

typedef unsigned int uint32;
typedef unsigned short u16;

#define TOK 1024
#define HID 2048
#define NEXP 64
#define TOPK 8
#define IMED 768
#define IMED2 1536

typedef __attribute__((ext_vector_type(8))) _Float16 half8;
typedef __attribute__((ext_vector_type(4))) float f32x4;

static __device__ __forceinline__ uint32 pack2(float a, float b) {
  union { _Float16 h[2]; uint32 u; } p;
  p.h[0] = (_Float16)a; p.h[1] = (_Float16)b;
  return p.u;
}
static __device__ __forceinline__ u16 f2h(float a) {
  union { _Float16 h; u16 u; } p;
  p.h = (_Float16)a;
  return p.u;
}
static __device__ __forceinline__ float h2f(u16 a) {
  union { _Float16 h; u16 u; } p;
  p.u = a;
  return (float)p.h;
}

// ---------------- x -> f16 pre-cast ----------------
__global__ void xcast_kernel(const float* __restrict__ x, u16* __restrict__ xh) {
  size_t i = (size_t)blockIdx.x * 256 + threadIdx.x;  // per 8 elements
  const float4* p = (const float4*)(x + i * 8);
  float4 v0 = p[0], v1 = p[1];
  uint4 o;
  o.x = pack2(v0.x, v0.y); o.y = pack2(v0.z, v0.w);
  o.z = pack2(v1.x, v1.y); o.w = pack2(v1.z, v1.w);
  *(uint4*)(xh + i * 8) = o;
}

// ---------------- router ----------------
__global__ void router_kernel(const float* __restrict__ x, const float* __restrict__ gw,
                              int* __restrict__ topk_id, float* __restrict__ topk_w,
                              int* __restrict__ cnt) {
  int t = blockIdx.x;
  __shared__ __align__(16) float xs[HID];
  __shared__ float part[4][NEXP];
  const float* xr = x + (size_t)t * HID;
  for (int i = threadIdx.x; i < HID / 4; i += 256)
    ((float4*)xs)[i] = ((const float4*)xr)[i];
  __syncthreads();
  int e = threadIdx.x & 63, p = threadIdx.x >> 6;
  const float* wr = gw + (size_t)e * HID + p * 512;
  const float* xp = xs + p * 512;
  float s = 0.f;
  #pragma unroll 4
  for (int i = 0; i < 128; i++) {
    float4 w = ((const float4*)wr)[i];
    float4 xv = ((const float4*)xp)[i];
    s += w.x * xv.x + w.y * xv.y + w.z * xv.z + w.w * xv.w;
  }
  part[p][e] = s;
  __syncthreads();
  if (threadIdx.x < 64) {
    int l = threadIdx.x;
    float lg = part[0][l] + part[1][l] + part[2][l] + part[3][l];
    float m = lg;
    #pragma unroll
    for (int d = 1; d < 64; d <<= 1) m = fmaxf(m, __shfl_xor(m, d));
    float v = __expf(lg - m);
    float w8[TOPK]; int i8[TOPK]; float wsum = 0.f;
    #pragma unroll
    for (int k = 0; k < TOPK; k++) {
      float bv = v; int bi = l;
      #pragma unroll
      for (int d = 1; d < 64; d <<= 1) {
        float ov = __shfl_xor(bv, d);
        int oi = __shfl_xor(bi, d);
        if (ov > bv || (ov == bv && oi < bi)) { bv = ov; bi = oi; }
      }
      w8[k] = bv; i8[k] = bi; wsum += bv;
      if (l == bi) v = -1.f;
    }
    if (l == 0) {
      float rinv = 1.f / wsum;
      #pragma unroll
      for (int k = 0; k < TOPK; k++) {
        topk_id[t * TOPK + k] = i8[k];
        topk_w[t * TOPK + k] = w8[k] * rinv;
        atomicAdd(&cnt[i8[k]], 1);
      }
    }
  }
}

__global__ void scan_kernel(const int* __restrict__ cnt, int* __restrict__ off,
                            int* __restrict__ cur) {
  if (threadIdx.x == 0) {
    int a = 0;
    for (int e = 0; e < NEXP; e++) { off[e] = a; cur[e] = a; a += cnt[e]; }
    off[NEXP] = a;
  }
}

__global__ void scatter_kernel(const int* __restrict__ topk_id, const float* __restrict__ topk_w,
                               int* __restrict__ cur, int* __restrict__ row_tok,
                               float* __restrict__ row_w) {
  int i = blockIdx.x * 256 + threadIdx.x;
  int e = topk_id[i];
  int p = atomicAdd(&cur[e], 1);
  row_tok[p] = i >> 3;
  row_w[p] = topk_w[i];
}

// ---------------- grouped gate_up GEMM + fused SwiGLU ----------------
// BM=256, BN=32(gate)+32(up), BK=32, 256 threads (4 waves, each owning 64 rows)
// single LDS buffer + 1-deep register prefetch (issue-early / write-late)
__global__ __launch_bounds__(256, 3) void gateup_kernel(
    const u16* __restrict__ xh, const float* __restrict__ Wgu,
    const int* __restrict__ off, const int* __restrict__ row_tok,
    u16* __restrict__ act) {
  int e = blockIdx.z;
  int r0 = off[e];
  int ne = off[e + 1] - r0;
  int m0 = blockIdx.y << 8;
  if (m0 >= ne) return;
  int i0h = blockIdx.x << 5;  // 32-col slab within each half

  __shared__ __align__(16) char AsB[256 * 80];
  __shared__ __align__(16) char BsB[64 * 80];

  int tid = threadIdx.x;
  int lane = tid & 63;
  int wid = tid >> 6;  // wave -> 64-row slab
  int fr = lane & 15, hi = lane >> 4;

  // A staging: 1 thread per row, 32 f16 (64B)
  int arow = tid;
  int grow = m0 + arow;
  int tok = row_tok[r0 + ((grow < ne) ? grow : 0)];
  const u16* xa = xh + (size_t)tok * HID;
  int axr = (arow >> 2) & 3;

  // B staging: thread -> 2 local cols x 4 k; local col 0..31 gate, 32..63 up
  int bn = (tid & 31) << 1;
  int bk = (tid >> 5) << 2;
  int gcol = (bn < 32) ? (i0h + bn) : (IMED + i0h + (bn - 32));
  const float* wb = Wgu + (size_t)e * ((size_t)HID * IMED2) + (size_t)bk * IMED2 + gcol;

  f32x4 accg[4][2], accu[4][2];
  #pragma unroll
  for (int a = 0; a < 4; a++)
    #pragma unroll
    for (int b = 0; b < 2; b++) { accg[a][b] = (f32x4)0.f; accu[a][b] = (f32x4)0.f; }

  uint4 q0, q1, q2, q3;
  float2 w0, w1, w2, w3;
  auto LOADT = [&]() {
    const uint4* p = (const uint4*)xa;
    q0 = p[0]; q1 = p[1]; q2 = p[2]; q3 = p[3];
    xa += 32;
    w0 = *(const float2*)(wb);
    w1 = *(const float2*)(wb + IMED2);
    w2 = *(const float2*)(wb + 2 * IMED2);
    w3 = *(const float2*)(wb + 3 * IMED2);
    wb += (size_t)32 * IMED2;
  };
  auto STORET = [&]() {
    char* A_ = AsB + arow * 80;
    *(uint4*)(A_ + ((0 ^ axr) << 4)) = q0;
    *(uint4*)(A_ + ((1 ^ axr) << 4)) = q1;
    *(uint4*)(A_ + ((2 ^ axr) << 4)) = q2;
    *(uint4*)(A_ + ((3 ^ axr) << 4)) = q3;
    uint2 p0, p1;
    p0.x = pack2(w0.x, w1.x); p0.y = pack2(w2.x, w3.x);
    p1.x = pack2(w0.y, w1.y); p1.y = pack2(w2.y, w3.y);
    int kb = (bk & 7) << 1;
    *(uint2*)(BsB + bn * 80 + ((((bk >> 3) ^ (bn >> 2)) & 3) << 4) + kb) = p0;
    *(uint2*)(BsB + (bn + 1) * 80 + ((((bk >> 3) ^ ((bn + 1) >> 2)) & 3) << 4) + kb) = p1;
  };

  const int NK = HID / 32;  // 64
  LOADT();
  STORET();
  LOADT();
  __syncthreads();

  for (int t = 0; t < NK; ++t) {
    half8 af[4];
    #pragma unroll
    for (int mi = 0; mi < 4; mi++) {
      int r = (wid << 6) + (mi << 4) + fr;
      af[mi] = *(half8*)(AsB + r * 80 + (((hi ^ (r >> 2)) & 3) << 4));
    }
    #pragma unroll
    for (int ni = 0; ni < 2; ni++) {
      int ng = (ni << 4) + fr;
      int nu = ng + 32;
      half8 bg = *(half8*)(BsB + ng * 80 + (((hi ^ (ng >> 2)) & 3) << 4));
      half8 bu = *(half8*)(BsB + nu * 80 + (((hi ^ (nu >> 2)) & 3) << 4));
      #pragma unroll
      for (int mi = 0; mi < 4; mi++) {
        accg[mi][ni] = __builtin_amdgcn_mfma_f32_16x16x32_f16(af[mi], bg, accg[mi][ni], 0, 0, 0);
        accu[mi][ni] = __builtin_amdgcn_mfma_f32_16x16x32_f16(af[mi], bu, accu[mi][ni], 0, 0, 0);
      }
    }
    __syncthreads();
    if (t + 1 < NK) {
      STORET();
      if (t + 2 < NK) LOADT();
      __syncthreads();
    }
  }

  // epilogue: SwiGLU -> act (f16)
  #pragma unroll
  for (int mi = 0; mi < 4; mi++) {
    #pragma unroll
    for (int ni = 0; ni < 2; ni++) {
      int col = i0h + (ni << 4) + fr;
      #pragma unroll
      for (int r = 0; r < 4; r++) {
        int rr = m0 + (wid << 6) + (mi << 4) + (hi << 2) + r;
        if (rr < ne) {
          float g = accg[mi][ni][r];
          float u = accu[mi][ni][r];
          float s = g / (1.f + __expf(-g)) * u;
          act[(size_t)(r0 + rr) * IMED + col] = f2h(s);
        }
      }
    }
  }
}

// ---------------- grouped down GEMM + weighted scatter-add ----------------
// BM=256, BN=64, BK=32, 256 threads (4 waves: 2m x 2n)
__global__ __launch_bounds__(256, 3) void down_kernel(
    const u16* __restrict__ act, const float* __restrict__ Wd,
    const int* __restrict__ off, const int* __restrict__ row_tok,
    const float* __restrict__ row_w, float* __restrict__ out) {
  int e = blockIdx.z;
  int r0 = off[e];
  int ne = off[e + 1] - r0;
  int m0 = blockIdx.y << 8;
  if (m0 >= ne) return;
  int n0 = blockIdx.x << 6;

  __shared__ __align__(16) char AsB[256 * 80];
  __shared__ __align__(16) char BsB[64 * 80];

  int tid = threadIdx.x;
  int lane = tid & 63;
  int wid = tid >> 6;
  int wm = wid >> 1, wn = wid & 1;
  int fr = lane & 15, hi = lane >> 4;

  // A staging: 1 thread per row, 32 f16 (64B) from act
  int arow = tid;
  int grow = m0 + arow;
  const u16* ap = act + (size_t)(r0 + ((grow < ne) ? grow : 0)) * IMED;
  int axr = (arow >> 2) & 3;

  // B staging: thread -> 2 cols x 4 k
  int bn = (tid & 31) << 1;
  int bk = (tid >> 5) << 2;
  const float* wb = Wd + (size_t)e * ((size_t)IMED * HID) + (size_t)bk * HID + n0 + bn;

  f32x4 acc[8][2];
  #pragma unroll
  for (int a = 0; a < 8; a++)
    #pragma unroll
    for (int b = 0; b < 2; b++) acc[a][b] = (f32x4)0.f;

  uint4 q0, q1, q2, q3;
  float2 w0, w1, w2, w3;
  auto LOADT = [&]() {
    const uint4* p = (const uint4*)ap;
    q0 = p[0]; q1 = p[1]; q2 = p[2]; q3 = p[3];
    ap += 32;
    w0 = *(const float2*)(wb);
    w1 = *(const float2*)(wb + HID);
    w2 = *(const float2*)(wb + 2 * HID);
    w3 = *(const float2*)(wb + 3 * HID);
    wb += (size_t)32 * HID;
  };
  auto STORET = [&]() {
    char* A_ = AsB + arow * 80;
    *(uint4*)(A_ + ((0 ^ axr) << 4)) = q0;
    *(uint4*)(A_ + ((1 ^ axr) << 4)) = q1;
    *(uint4*)(A_ + ((2 ^ axr) << 4)) = q2;
    *(uint4*)(A_ + ((3 ^ axr) << 4)) = q3;
    uint2 p0, p1;
    p0.x = pack2(w0.x, w1.x); p0.y = pack2(w2.x, w3.x);
    p1.x = pack2(w0.y, w1.y); p1.y = pack2(w2.y, w3.y);
    int kb = (bk & 7) << 1;
    *(uint2*)(BsB + bn * 80 + ((((bk >> 3) ^ (bn >> 2)) & 3) << 4) + kb) = p0;
    *(uint2*)(BsB + (bn + 1) * 80 + ((((bk >> 3) ^ ((bn + 1) >> 2)) & 3) << 4) + kb) = p1;
  };

  const int NK = IMED / 32;  // 24
  LOADT();
  STORET();
  LOADT();
  __syncthreads();

  for (int t = 0; t < NK; ++t) {
    half8 af[8];
    #pragma unroll
    for (int mi = 0; mi < 8; mi++) {
      int r = (wm << 7) + (mi << 4) + fr;
      af[mi] = *(half8*)(AsB + r * 80 + (((hi ^ (r >> 2)) & 3) << 4));
    }
    #pragma unroll
    for (int ni = 0; ni < 2; ni++) {
      int n = (wn << 5) + (ni << 4) + fr;
      half8 bf_ = *(half8*)(BsB + n * 80 + (((hi ^ (n >> 2)) & 3) << 4));
      #pragma unroll
      for (int mi = 0; mi < 8; mi++)
        acc[mi][ni] = __builtin_amdgcn_mfma_f32_16x16x32_f16(af[mi], bf_, acc[mi][ni], 0, 0, 0);
    }
    __syncthreads();
    if (t + 1 < NK) {
      STORET();
      if (t + 2 < NK) LOADT();
      __syncthreads();
    }
  }

  #pragma unroll
  for (int mi = 0; mi < 8; mi++) {
    #pragma unroll
    for (int r = 0; r < 4; r++) {
      int rr = m0 + (wm << 7) + (mi << 4) + (hi << 2) + r;
      if (rr < ne) {
        float w = row_w[r0 + rr];
        int t = row_tok[r0 + rr];
        #pragma unroll
        for (int ni = 0; ni < 2; ni++) {
          int col = n0 + (wn << 5) + (ni << 4) + fr;
          unsafeAtomicAdd(&out[(size_t)t * HID + col], acc[mi][ni][r] * w);
        }
      }
    }
  }
}

// ---------------- launch ----------------
extern "C" void kernel_launch(void* const* d_in, const int* in_sizes, int n_in,
                              void* d_out, int out_size, void* d_ws, size_t ws_size,
                              hipStream_t stream) {
  const float* x = (const float*)d_in[0];
  const float* gw = (const float*)d_in[1];
  const float* wgu = (const float*)d_in[2];
  const float* wd = (const float*)d_in[3];
  float* out = (float*)d_out;
  char* ws = (char*)d_ws;

  int* cnt = (int*)(ws + 0);
  int* cur = (int*)(ws + 256);
  int* off = (int*)(ws + 512);
  int* topk_id = (int*)(ws + 1024);
  float* topk_w = (float*)(ws + 1024 + 32768);
  int* row_tok = (int*)(ws + 1024 + 65536);
  float* row_w = (float*)(ws + 1024 + 98304);
  u16* act = (u16*)(ws + 135168);                      // 8192*768*2 = 12.6 MB
  u16* xh = (u16*)(ws + 135168 + (size_t)TOK * TOPK * IMED * 2);  // 4.2 MB

  hipMemsetAsync(cnt, 0, 256, stream);
  xcast_kernel<<<TOK * HID / 8 / 256, 256, 0, stream>>>(x, xh);
  router_kernel<<<TOK, 256, 0, stream>>>(x, gw, topk_id, topk_w, cnt);
  scan_kernel<<<1, 64, 0, stream>>>(cnt, off, cur);
  scatter_kernel<<<TOK * TOPK / 256, 256, 0, stream>>>(topk_id, topk_w, cur, row_tok, row_w);
  gateup_kernel<<<dim3(IMED / 32, 4, NEXP), 256, 0, stream>>>(xh, wgu, off, row_tok, act);
  hipMemsetAsync(out, 0, (size_t)TOK * HID * sizeof(float), stream);
  down_kernel<<<dim3(HID / 64, 4, NEXP), 256, 0, stream>>>(act, wd, off, row_tok, row_w, out);
}

// Round 4
// 420.166 us; speedup vs baseline: 1.5879x; 1.5879x over previous
//
#include <hip/hip_runtime.h>
#include <hip/hip_bf16.h>
#include <hip/hip_fp16.h>

typedef unsigned int uint32;
typedef unsigned short u16;

#define TOK 1024
#define HID 2048
#define NEXP 64
#define TOPK 8
#define IMED 768
#define IMED2 1536

typedef __attribute__((ext_vector_type(8))) _Float16 half8;
typedef __attribute__((ext_vector_type(4))) float f32x4;

static __device__ __forceinline__ uint32 pack2(float a, float b) {
  union { _Float16 h[2]; uint32 u; } p;
  p.h[0] = (_Float16)a; p.h[1] = (_Float16)b;
  return p.u;
}
static __device__ __forceinline__ u16 f2h(float a) {
  union { _Float16 h; u16 u; } p;
  p.h = (_Float16)a;
  return p.u;
}

// ---------------- x -> f16 pre-cast ----------------
__global__ void xcast_kernel(const float* __restrict__ x, u16* __restrict__ xh) {
  size_t i = (size_t)blockIdx.x * 256 + threadIdx.x;
  const float4* p = (const float4*)(x + i * 8);
  float4 v0 = p[0], v1 = p[1];
  uint4 o;
  o.x = pack2(v0.x, v0.y); o.y = pack2(v0.z, v0.w);
  o.z = pack2(v1.x, v1.y); o.w = pack2(v1.z, v1.w);
  *(uint4*)(xh + i * 8) = o;
}

// ---------------- router ----------------
__global__ void router_kernel(const float* __restrict__ x, const float* __restrict__ gw,
                              int* __restrict__ topk_id, float* __restrict__ topk_w,
                              int* __restrict__ cnt) {
  int t = blockIdx.x;
  __shared__ __align__(16) float xs[HID];
  __shared__ float part[4][NEXP];
  const float* xr = x + (size_t)t * HID;
  for (int i = threadIdx.x; i < HID / 4; i += 256)
    ((float4*)xs)[i] = ((const float4*)xr)[i];
  __syncthreads();
  int e = threadIdx.x & 63, p = threadIdx.x >> 6;
  const float* wr = gw + (size_t)e * HID + p * 512;
  const float* xp = xs + p * 512;
  float s = 0.f;
  #pragma unroll 4
  for (int i = 0; i < 128; i++) {
    float4 w = ((const float4*)wr)[i];
    float4 xv = ((const float4*)xp)[i];
    s += w.x * xv.x + w.y * xv.y + w.z * xv.z + w.w * xv.w;
  }
  part[p][e] = s;
  __syncthreads();
  if (threadIdx.x < 64) {
    int l = threadIdx.x;
    float lg = part[0][l] + part[1][l] + part[2][l] + part[3][l];
    float m = lg;
    #pragma unroll
    for (int d = 1; d < 64; d <<= 1) m = fmaxf(m, __shfl_xor(m, d));
    float v = __expf(lg - m);
    float w8[TOPK]; int i8[TOPK]; float wsum = 0.f;
    #pragma unroll
    for (int k = 0; k < TOPK; k++) {
      float bv = v; int bi = l;
      #pragma unroll
      for (int d = 1; d < 64; d <<= 1) {
        float ov = __shfl_xor(bv, d);
        int oi = __shfl_xor(bi, d);
        if (ov > bv || (ov == bv && oi < bi)) { bv = ov; bi = oi; }
      }
      w8[k] = bv; i8[k] = bi; wsum += bv;
      if (l == bi) v = -1.f;
    }
    if (l == 0) {
      float rinv = 1.f / wsum;
      #pragma unroll
      for (int k = 0; k < TOPK; k++) {
        topk_id[t * TOPK + k] = i8[k];
        topk_w[t * TOPK + k] = w8[k] * rinv;
        atomicAdd(&cnt[i8[k]], 1);
      }
    }
  }
}

__global__ void scan_kernel(const int* __restrict__ cnt, int* __restrict__ off,
                            int* __restrict__ cur) {
  if (threadIdx.x == 0) {
    int a = 0;
    for (int e = 0; e < NEXP; e++) { off[e] = a; cur[e] = a; a += cnt[e]; }
    off[NEXP] = a;
  }
}

__global__ void scatter_kernel(const int* __restrict__ topk_id, const float* __restrict__ topk_w,
                               int* __restrict__ cur, int* __restrict__ row_tok,
                               float* __restrict__ row_w) {
  int i = blockIdx.x * 256 + threadIdx.x;
  int e = topk_id[i];
  int p = atomicAdd(&cur[e], 1);
  row_tok[p] = i >> 3;
  row_w[p] = topk_w[i];
}

// ---------------- grouped gate_up GEMM + fused SwiGLU ----------------
// BM=256 (covers ne), BN=96 gate + 96 up, BK=32, 512 threads (8 waves 4m x 2n)
// single LDS buffer, 1-deep register prefetch, XCD-bijective block remap
__global__ __launch_bounds__(512, 2) void gateup_kernel(
    const u16* __restrict__ xh, const float* __restrict__ Wgu,
    const int* __restrict__ off, const int* __restrict__ row_tok,
    u16* __restrict__ act) {
  int bid = blockIdx.x;                 // 512 blocks
  int xcd = bid & 7, s2 = bid >> 3;
  int e = xcd + ((s2 & 7) << 3);        // all slabs of expert e on one XCD
  int slab = s2 >> 3;                   // 0..7
  int r0 = off[e];
  int ne = off[e + 1] - r0;
  int c0 = slab * 96;

  __shared__ __align__(16) char AsB[256 * 80];  // 20KB
  __shared__ __align__(16) char BsB[192 * 80];  // 15KB

  int tid = threadIdx.x;
  int lane = tid & 63;
  int wid = tid >> 6;
  int wm = wid >> 1, wn = wid & 1;      // 4m x 2n
  int fr = lane & 15, hi = lane >> 4;

  // A stage: 2 threads/row, 16 f16 each
  int arow = tid >> 1, aseg = tid & 1;
  int tok = row_tok[r0 + ((arow < ne) ? arow : 0)];
  const u16* xa = xh + (size_t)tok * HID + (aseg << 4);
  int axr = (arow >> 2) & 3;

  // B stage: tid<384: cg (col quad), h (gate/up), kq (k quad)
  bool bact = tid < 384;
  int cg = tid % 24, h = (tid / 24) & 1, kq = tid / 48;  // kq 0..7
  int bcol = cg << 2;
  int gc = h ? (IMED + c0 + bcol) : (c0 + bcol);
  const float* wb = Wgu + (size_t)e * ((size_t)HID * IMED2) + (size_t)(kq << 2) * IMED2 + gc;
  int brbase = 96 * h + bcol;

  f32x4 accg[4][3], accu[4][3];
  #pragma unroll
  for (int a = 0; a < 4; a++)
    #pragma unroll
    for (int b = 0; b < 3; b++) { accg[a][b] = (f32x4)0.f; accu[a][b] = (f32x4)0.f; }

  uint4 qa0, qa1;
  float4 w0, w1, w2, w3;
  auto LOADT = [&]() {
    const uint4* p = (const uint4*)xa;
    qa0 = p[0]; qa1 = p[1];
    xa += 32;
    if (bact) {
      w0 = *(const float4*)(wb);
      w1 = *(const float4*)(wb + IMED2);
      w2 = *(const float4*)(wb + 2 * IMED2);
      w3 = *(const float4*)(wb + 3 * IMED2);
    }
    wb += (size_t)32 * IMED2;
  };
  auto STORET = [&]() {
    char* A_ = AsB + arow * 80;
    int g0 = aseg << 1;
    *(uint4*)(A_ + (((g0 + 0) ^ axr) << 4)) = qa0;
    *(uint4*)(A_ + (((g0 + 1) ^ axr) << 4)) = qa1;
    if (bact) {
      float c0v[4] = {w0.x, w0.y, w0.z, w0.w};
      float c1v[4] = {w1.x, w1.y, w1.z, w1.w};
      float c2v[4] = {w2.x, w2.y, w2.z, w2.w};
      float c3v[4] = {w3.x, w3.y, w3.z, w3.w};
      int kg = kq >> 1, kb = (kq & 1) << 3;
      #pragma unroll
      for (int cc = 0; cc < 4; cc++) {
        int br = brbase + cc;
        uint2 pv;
        pv.x = pack2(c0v[cc], c1v[cc]);
        pv.y = pack2(c2v[cc], c3v[cc]);
        *(uint2*)(BsB + br * 80 + (((kg ^ (br >> 2)) & 3) << 4) + kb) = pv;
      }
    }
  };

  const int NK = HID / 32;  // 64
  LOADT();
  STORET();
  LOADT();
  __syncthreads();

  for (int t = 0; t < NK; ++t) {
    half8 af[4];
    #pragma unroll
    for (int mi = 0; mi < 4; mi++) {
      int r = (wm << 6) + (mi << 4) + fr;
      af[mi] = *(half8*)(AsB + r * 80 + (((hi ^ (r >> 2)) & 3) << 4));
    }
    #pragma unroll
    for (int ni = 0; ni < 3; ni++) {
      int ng = (wn * 48) + (ni << 4) + fr;
      int nu = ng + 96;
      half8 bg = *(half8*)(BsB + ng * 80 + (((hi ^ (ng >> 2)) & 3) << 4));
      half8 bu = *(half8*)(BsB + nu * 80 + (((hi ^ (nu >> 2)) & 3) << 4));
      #pragma unroll
      for (int mi = 0; mi < 4; mi++) {
        accg[mi][ni] = __builtin_amdgcn_mfma_f32_16x16x32_f16(af[mi], bg, accg[mi][ni], 0, 0, 0);
        accu[mi][ni] = __builtin_amdgcn_mfma_f32_16x16x32_f16(af[mi], bu, accu[mi][ni], 0, 0, 0);
      }
    }
    __syncthreads();
    if (t + 1 < NK) {
      STORET();
      if (t + 2 < NK) LOADT();
      __syncthreads();
    }
  }

  // epilogue: SwiGLU -> act (f16)
  #pragma unroll
  for (int mi = 0; mi < 4; mi++) {
    #pragma unroll
    for (int ni = 0; ni < 3; ni++) {
      int col = c0 + wn * 48 + (ni << 4) + fr;
      #pragma unroll
      for (int r = 0; r < 4; r++) {
        int rr = (wm << 6) + (mi << 4) + (hi << 2) + r;
        if (rr < ne) {
          float g = accg[mi][ni][r];
          float u = accu[mi][ni][r];
          float s = g / (1.f + __expf(-g)) * u;
          act[(size_t)(r0 + rr) * IMED + col] = f2h(s);
        }
      }
    }
  }
}

// ---------------- grouped down GEMM + weighted scatter-add ----------------
// BM=256, BN=256, BK=32, 512 threads (8 waves 4m x 2n)
__global__ __launch_bounds__(512, 2) void down_kernel(
    const u16* __restrict__ act, const float* __restrict__ Wd,
    const int* __restrict__ off, const int* __restrict__ row_tok,
    const float* __restrict__ row_w, float* __restrict__ out) {
  int bid = blockIdx.x;                 // 512 blocks
  int xcd = bid & 7, s2 = bid >> 3;
  int e = xcd + ((s2 & 7) << 3);
  int slab = s2 >> 3;                   // 0..7
  int r0 = off[e];
  int ne = off[e + 1] - r0;
  int n0 = slab << 8;

  __shared__ __align__(16) char AsB[256 * 80];  // 20KB
  __shared__ __align__(16) char BsB[256 * 80];  // 20KB

  int tid = threadIdx.x;
  int lane = tid & 63;
  int wid = tid >> 6;
  int wm = wid >> 1, wn = wid & 1;
  int fr = lane & 15, hi = lane >> 4;

  // A stage: 2 threads/row, 16 f16 each from act
  int arow = tid >> 1, aseg = tid & 1;
  const u16* ap = act + (size_t)(r0 + ((arow < ne) ? arow : 0)) * IMED + (aseg << 4);
  int axr = (arow >> 2) & 3;

  // B stage: cq = col quad (0..63), kq = k quad (0..7)
  int cq = tid & 63, kq = tid >> 6;
  int bcol = cq << 2;
  const float* wb = Wd + (size_t)e * ((size_t)IMED * HID) + (size_t)(kq << 2) * HID + n0 + bcol;

  f32x4 acc[4][8];
  #pragma unroll
  for (int a = 0; a < 4; a++)
    #pragma unroll
    for (int b = 0; b < 8; b++) acc[a][b] = (f32x4)0.f;

  uint4 qa0, qa1;
  float4 w0, w1, w2, w3;
  auto LOADT = [&]() {
    const uint4* p = (const uint4*)ap;
    qa0 = p[0]; qa1 = p[1];
    ap += 32;
    w0 = *(const float4*)(wb);
    w1 = *(const float4*)(wb + HID);
    w2 = *(const float4*)(wb + 2 * HID);
    w3 = *(const float4*)(wb + 3 * HID);
    wb += (size_t)32 * HID;
  };
  auto STORET = [&]() {
    char* A_ = AsB + arow * 80;
    int g0 = aseg << 1;
    *(uint4*)(A_ + (((g0 + 0) ^ axr) << 4)) = qa0;
    *(uint4*)(A_ + (((g0 + 1) ^ axr) << 4)) = qa1;
    float c0v[4] = {w0.x, w0.y, w0.z, w0.w};
    float c1v[4] = {w1.x, w1.y, w1.z, w1.w};
    float c2v[4] = {w2.x, w2.y, w2.z, w2.w};
    float c3v[4] = {w3.x, w3.y, w3.z, w3.w};
    int kg = kq >> 1, kb = (kq & 1) << 3;
    #pragma unroll
    for (int cc = 0; cc < 4; cc++) {
      int br = bcol + cc;
      uint2 pv;
      pv.x = pack2(c0v[cc], c1v[cc]);
      pv.y = pack2(c2v[cc], c3v[cc]);
      *(uint2*)(BsB + br * 80 + (((kg ^ (br >> 2)) & 3) << 4) + kb) = pv;
    }
  };

  const int NK = IMED / 32;  // 24
  LOADT();
  STORET();
  LOADT();
  __syncthreads();

  for (int t = 0; t < NK; ++t) {
    half8 af[4];
    #pragma unroll
    for (int mi = 0; mi < 4; mi++) {
      int r = (wm << 6) + (mi << 4) + fr;
      af[mi] = *(half8*)(AsB + r * 80 + (((hi ^ (r >> 2)) & 3) << 4));
    }
    #pragma unroll
    for (int ni = 0; ni < 8; ni++) {
      int n = (wn << 7) + (ni << 4) + fr;
      half8 bf_ = *(half8*)(BsB + n * 80 + (((hi ^ (n >> 2)) & 3) << 4));
      #pragma unroll
      for (int mi = 0; mi < 4; mi++)
        acc[mi][ni] = __builtin_amdgcn_mfma_f32_16x16x32_f16(af[mi], bf_, acc[mi][ni], 0, 0, 0);
    }
    __syncthreads();
    if (t + 1 < NK) {
      STORET();
      if (t + 2 < NK) LOADT();
      __syncthreads();
    }
  }

  #pragma unroll
  for (int mi = 0; mi < 4; mi++) {
    #pragma unroll
    for (int r = 0; r < 4; r++) {
      int rr = (wm << 6) + (mi << 4) + (hi << 2) + r;
      if (rr < ne) {
        float w = row_w[r0 + rr];
        int t = row_tok[r0 + rr];
        #pragma unroll
        for (int ni = 0; ni < 8; ni++) {
          int col = n0 + (wn << 7) + (ni << 4) + fr;
          unsafeAtomicAdd(&out[(size_t)t * HID + col], acc[mi][ni][r] * w);
        }
      }
    }
  }
}

// ---------------- launch ----------------
extern "C" void kernel_launch(void* const* d_in, const int* in_sizes, int n_in,
                              void* d_out, int out_size, void* d_ws, size_t ws_size,
                              hipStream_t stream) {
  const float* x = (const float*)d_in[0];
  const float* gw = (const float*)d_in[1];
  const float* wgu = (const float*)d_in[2];
  const float* wd = (const float*)d_in[3];
  float* out = (float*)d_out;
  char* ws = (char*)d_ws;

  int* cnt = (int*)(ws + 0);
  int* cur = (int*)(ws + 256);
  int* off = (int*)(ws + 512);
  int* topk_id = (int*)(ws + 1024);
  float* topk_w = (float*)(ws + 1024 + 32768);
  int* row_tok = (int*)(ws + 1024 + 65536);
  float* row_w = (float*)(ws + 1024 + 98304);
  u16* act = (u16*)(ws + 135168);                                  // 12.6 MB
  u16* xh = (u16*)(ws + 135168 + (size_t)TOK * TOPK * IMED * 2);   // 4.2 MB

  hipMemsetAsync(cnt, 0, 256, stream);
  xcast_kernel<<<TOK * HID / 8 / 256, 256, 0, stream>>>(x, xh);
  router_kernel<<<TOK, 256, 0, stream>>>(x, gw, topk_id, topk_w, cnt);
  scan_kernel<<<1, 64, 0, stream>>>(cnt, off, cur);
  scatter_kernel<<<TOK * TOPK / 256, 256, 0, stream>>>(topk_id, topk_w, cur, row_tok, row_w);
  gateup_kernel<<<512, 512, 0, stream>>>(xh, wgu, off, row_tok, act);
  hipMemsetAsync(out, 0, (size_t)TOK * HID * sizeof(float), stream);
  down_kernel<<<512, 512, 0, stream>>>(act, wd, off, row_tok, row_w, out);
}

// Round 5
// 392.870 us; speedup vs baseline: 1.6983x; 1.0695x over previous
//
#include <hip/hip_runtime.h>
#include <hip/hip_bf16.h>
#include <hip/hip_fp16.h>

typedef unsigned int uint32;
typedef unsigned short u16;

#define TOK 1024
#define HID 2048
#define NEXP 64
#define TOPK 8
#define IMED 768
#define IMED2 1536

typedef __attribute__((ext_vector_type(8))) _Float16 half8;
typedef __attribute__((ext_vector_type(4))) float f32x4;

static __device__ __forceinline__ uint32 pack2(float a, float b) {
  union { _Float16 h[2]; uint32 u; } p;
  p.h[0] = (_Float16)a; p.h[1] = (_Float16)b;
  return p.u;
}
static __device__ __forceinline__ u16 f2h(float a) {
  union { _Float16 h; u16 u; } p;
  p.h = (_Float16)a;
  return p.u;
}

// ---------------- router: logits -> top8 -> renorm; also emits xh (f16 x) ---
// 256 blocks x 4 tokens. Within a wave all 64 lanes read the SAME x address
// (L1 broadcast) while each lane streams one gw row (L1-line reuse across i).
__global__ __launch_bounds__(256) void router_kernel(
    const float* __restrict__ x, const float* __restrict__ gw,
    int* __restrict__ topk_id, float* __restrict__ topk_w,
    u16* __restrict__ xh) {
  int t0 = blockIdx.x << 2;
  __shared__ float part[4][NEXP][5];
  int tid = threadIdx.x;
  int e = tid & 63, p = tid >> 6;
  const float* gwp = gw + (size_t)e * HID + (p << 9);
  const float* xp = x + (size_t)t0 * HID + (p << 9);
  float acc[4] = {0.f, 0.f, 0.f, 0.f};
  for (int i = 0; i < 128; i++) {
    float4 w = ((const float4*)gwp)[i];
    #pragma unroll
    for (int t = 0; t < 4; t++) {
      float4 xv = *(const float4*)(xp + (size_t)t * HID + (i << 2));
      acc[t] += w.x * xv.x + w.y * xv.y + w.z * xv.z + w.w * xv.w;
    }
  }
  #pragma unroll
  for (int t = 0; t < 4; t++) part[p][e][t] = acc[t];
  // emit xh for these 4 tokens: 4 rows x 512 float4 = 2048 units
  for (int i = tid; i < 2048; i += 256) {
    int r = i >> 9;
    int c = i & 511;
    float4 v = *(const float4*)(x + (size_t)(t0 + r) * HID + (c << 2));
    uint2 hp;
    hp.x = pack2(v.x, v.y);
    hp.y = pack2(v.z, v.w);
    *(uint2*)(xh + (size_t)(t0 + r) * HID + (c << 2)) = hp;
  }
  __syncthreads();
  // wave wv reduces + top8's token wv
  int wv = tid >> 6, l = tid & 63;
  int t = t0 + wv;
  float lg = part[0][l][wv] + part[1][l][wv] + part[2][l][wv] + part[3][l][wv];
  float m = lg;
  #pragma unroll
  for (int d = 1; d < 64; d <<= 1) m = fmaxf(m, __shfl_xor(m, d));
  float v = __expf(lg - m);
  float w8[TOPK]; int i8[TOPK]; float wsum = 0.f;
  #pragma unroll
  for (int k = 0; k < TOPK; k++) {
    float bv = v; int bi = l;
    #pragma unroll
    for (int d = 1; d < 64; d <<= 1) {
      float ov = __shfl_xor(bv, d);
      int oi = __shfl_xor(bi, d);
      if (ov > bv || (ov == bv && oi < bi)) { bv = ov; bi = oi; }
    }
    w8[k] = bv; i8[k] = bi; wsum += bv;
    if (l == bi) v = -1.f;
  }
  if (l == 0) {
    float rinv = 1.f / wsum;
    #pragma unroll
    for (int k = 0; k < TOPK; k++) {
      topk_id[t * TOPK + k] = i8[k];
      topk_w[t * TOPK + k] = w8[k] * rinv;
    }
  }
}

// ---------------- fused count + prefix + scatter (one block) ----------------
__global__ __launch_bounds__(256) void scan_scatter_kernel(
    const int* __restrict__ topk_id, const float* __restrict__ topk_w,
    int* __restrict__ off, int* __restrict__ row_tok, float* __restrict__ row_w) {
  __shared__ int scnt[NEXP];
  __shared__ int soff[NEXP + 1];
  __shared__ int scur[NEXP];
  int tid = threadIdx.x;
  if (tid < NEXP) scnt[tid] = 0;
  __syncthreads();
  for (int i = tid; i < TOK * TOPK; i += 256) atomicAdd(&scnt[topk_id[i]], 1);
  __syncthreads();
  if (tid == 0) {
    int a = 0;
    for (int e = 0; e < NEXP; e++) { soff[e] = a; a += scnt[e]; }
    soff[NEXP] = a;
  }
  __syncthreads();
  if (tid < NEXP) scur[tid] = soff[tid];
  __syncthreads();
  for (int i = tid; i < TOK * TOPK; i += 256) {
    int e = topk_id[i];
    int p = atomicAdd(&scur[e], 1);
    row_tok[p] = i >> 3;
    row_w[p] = topk_w[i];
  }
  if (tid < NEXP + 1) off[tid] = soff[tid];
}

// ---------------- grouped gate_up GEMM + fused SwiGLU ----------------
// BM=256 (covers ne), BN=96 gate + 96 up, BK=32, 512 threads (8 waves 4m x 2n)
// single LDS buffer, 1-deep register prefetch, XCD-bijective block remap
__global__ __launch_bounds__(512, 2) void gateup_kernel(
    const u16* __restrict__ xh, const float* __restrict__ Wgu,
    const int* __restrict__ off, const int* __restrict__ row_tok,
    u16* __restrict__ act) {
  int bid = blockIdx.x;                 // 512 blocks
  int xcd = bid & 7, s2 = bid >> 3;
  int e = xcd + ((s2 & 7) << 3);        // all slabs of expert e on one XCD
  int slab = s2 >> 3;                   // 0..7
  int r0 = off[e];
  int ne = off[e + 1] - r0;
  int c0 = slab * 96;

  __shared__ __align__(16) char AsB[256 * 80];  // 20KB
  __shared__ __align__(16) char BsB[192 * 80];  // 15KB

  int tid = threadIdx.x;
  int lane = tid & 63;
  int wid = tid >> 6;
  int wm = wid >> 1, wn = wid & 1;      // 4m x 2n
  int fr = lane & 15, hi = lane >> 4;

  // A stage: 2 threads/row, 16 f16 each
  int arow = tid >> 1, aseg = tid & 1;
  int tok = row_tok[r0 + ((arow < ne) ? arow : 0)];
  const u16* xa = xh + (size_t)tok * HID + (aseg << 4);
  int axr = (arow >> 2) & 3;

  // B stage: tid<384: cg (col quad), h (gate/up), kq (k quad)
  bool bact = tid < 384;
  int cg = tid % 24, h = (tid / 24) & 1, kq = tid / 48;  // kq 0..7
  int bcol = cg << 2;
  int gc = h ? (IMED + c0 + bcol) : (c0 + bcol);
  const float* wb = Wgu + (size_t)e * ((size_t)HID * IMED2) + (size_t)(kq << 2) * IMED2 + gc;
  int brbase = 96 * h + bcol;

  f32x4 accg[4][3], accu[4][3];
  #pragma unroll
  for (int a = 0; a < 4; a++)
    #pragma unroll
    for (int b = 0; b < 3; b++) { accg[a][b] = (f32x4)0.f; accu[a][b] = (f32x4)0.f; }

  uint4 qa0, qa1;
  float4 w0, w1, w2, w3;
  auto LOADT = [&]() {
    const uint4* p = (const uint4*)xa;
    qa0 = p[0]; qa1 = p[1];
    xa += 32;
    if (bact) {
      w0 = *(const float4*)(wb);
      w1 = *(const float4*)(wb + IMED2);
      w2 = *(const float4*)(wb + 2 * IMED2);
      w3 = *(const float4*)(wb + 3 * IMED2);
    }
    wb += (size_t)32 * IMED2;
  };
  auto STORET = [&]() {
    char* A_ = AsB + arow * 80;
    int g0 = aseg << 1;
    *(uint4*)(A_ + (((g0 + 0) ^ axr) << 4)) = qa0;
    *(uint4*)(A_ + (((g0 + 1) ^ axr) << 4)) = qa1;
    if (bact) {
      float c0v[4] = {w0.x, w0.y, w0.z, w0.w};
      float c1v[4] = {w1.x, w1.y, w1.z, w1.w};
      float c2v[4] = {w2.x, w2.y, w2.z, w2.w};
      float c3v[4] = {w3.x, w3.y, w3.z, w3.w};
      int kg = kq >> 1, kb = (kq & 1) << 3;
      #pragma unroll
      for (int cc = 0; cc < 4; cc++) {
        int br = brbase + cc;
        uint2 pv;
        pv.x = pack2(c0v[cc], c1v[cc]);
        pv.y = pack2(c2v[cc], c3v[cc]);
        *(uint2*)(BsB + br * 80 + (((kg ^ (br >> 2)) & 3) << 4) + kb) = pv;
      }
    }
  };

  const int NK = HID / 32;  // 64
  LOADT();
  STORET();
  LOADT();
  __syncthreads();

  for (int t = 0; t < NK; ++t) {
    half8 af[4];
    #pragma unroll
    for (int mi = 0; mi < 4; mi++) {
      int r = (wm << 6) + (mi << 4) + fr;
      af[mi] = *(half8*)(AsB + r * 80 + (((hi ^ (r >> 2)) & 3) << 4));
    }
    #pragma unroll
    for (int ni = 0; ni < 3; ni++) {
      int ng = (wn * 48) + (ni << 4) + fr;
      int nu = ng + 96;
      half8 bg = *(half8*)(BsB + ng * 80 + (((hi ^ (ng >> 2)) & 3) << 4));
      half8 bu = *(half8*)(BsB + nu * 80 + (((hi ^ (nu >> 2)) & 3) << 4));
      #pragma unroll
      for (int mi = 0; mi < 4; mi++) {
        accg[mi][ni] = __builtin_amdgcn_mfma_f32_16x16x32_f16(af[mi], bg, accg[mi][ni], 0, 0, 0);
        accu[mi][ni] = __builtin_amdgcn_mfma_f32_16x16x32_f16(af[mi], bu, accu[mi][ni], 0, 0, 0);
      }
    }
    __syncthreads();
    if (t + 1 < NK) {
      STORET();
      if (t + 2 < NK) LOADT();
      __syncthreads();
    }
  }

  // epilogue: SwiGLU -> act (f16)
  #pragma unroll
  for (int mi = 0; mi < 4; mi++) {
    #pragma unroll
    for (int ni = 0; ni < 3; ni++) {
      int col = c0 + wn * 48 + (ni << 4) + fr;
      #pragma unroll
      for (int r = 0; r < 4; r++) {
        int rr = (wm << 6) + (mi << 4) + (hi << 2) + r;
        if (rr < ne) {
          float g = accg[mi][ni][r];
          float u = accu[mi][ni][r];
          float s = g / (1.f + __expf(-g)) * u;
          act[(size_t)(r0 + rr) * IMED + col] = f2h(s);
        }
      }
    }
  }
}

// ---------------- grouped down GEMM + weighted scatter-add ----------------
// BM=256, BN=256, BK=32, 512 threads (8 waves 4m x 2n)
__global__ __launch_bounds__(512, 2) void down_kernel(
    const u16* __restrict__ act, const float* __restrict__ Wd,
    const int* __restrict__ off, const int* __restrict__ row_tok,
    const float* __restrict__ row_w, float* __restrict__ out) {
  int bid = blockIdx.x;                 // 512 blocks
  int xcd = bid & 7, s2 = bid >> 3;
  int e = xcd + ((s2 & 7) << 3);
  int slab = s2 >> 3;                   // 0..7
  int r0 = off[e];
  int ne = off[e + 1] - r0;
  int n0 = slab << 8;

  __shared__ __align__(16) char AsB[256 * 80];  // 20KB
  __shared__ __align__(16) char BsB[256 * 80];  // 20KB

  int tid = threadIdx.x;
  int lane = tid & 63;
  int wid = tid >> 6;
  int wm = wid >> 1, wn = wid & 1;
  int fr = lane & 15, hi = lane >> 4;

  // A stage: 2 threads/row, 16 f16 each from act
  int arow = tid >> 1, aseg = tid & 1;
  const u16* ap = act + (size_t)(r0 + ((arow < ne) ? arow : 0)) * IMED + (aseg << 4);
  int axr = (arow >> 2) & 3;

  // B stage: cq = col quad (0..63), kq = k quad (0..7)
  int cq = tid & 63, kq = tid >> 6;
  int bcol = cq << 2;
  const float* wb = Wd + (size_t)e * ((size_t)IMED * HID) + (size_t)(kq << 2) * HID + n0 + bcol;

  f32x4 acc[4][8];
  #pragma unroll
  for (int a = 0; a < 4; a++)
    #pragma unroll
    for (int b = 0; b < 8; b++) acc[a][b] = (f32x4)0.f;

  uint4 qa0, qa1;
  float4 w0, w1, w2, w3;
  auto LOADT = [&]() {
    const uint4* p = (const uint4*)ap;
    qa0 = p[0]; qa1 = p[1];
    ap += 32;
    w0 = *(const float4*)(wb);
    w1 = *(const float4*)(wb + HID);
    w2 = *(const float4*)(wb + 2 * HID);
    w3 = *(const float4*)(wb + 3 * HID);
    wb += (size_t)32 * HID;
  };
  auto STORET = [&]() {
    char* A_ = AsB + arow * 80;
    int g0 = aseg << 1;
    *(uint4*)(A_ + (((g0 + 0) ^ axr) << 4)) = qa0;
    *(uint4*)(A_ + (((g0 + 1) ^ axr) << 4)) = qa1;
    float c0v[4] = {w0.x, w0.y, w0.z, w0.w};
    float c1v[4] = {w1.x, w1.y, w1.z, w1.w};
    float c2v[4] = {w2.x, w2.y, w2.z, w2.w};
    float c3v[4] = {w3.x, w3.y, w3.z, w3.w};
    int kg = kq >> 1, kb = (kq & 1) << 3;
    #pragma unroll
    for (int cc = 0; cc < 4; cc++) {
      int br = bcol + cc;
      uint2 pv;
      pv.x = pack2(c0v[cc], c1v[cc]);
      pv.y = pack2(c2v[cc], c3v[cc]);
      *(uint2*)(BsB + br * 80 + (((kg ^ (br >> 2)) & 3) << 4) + kb) = pv;
    }
  };

  const int NK = IMED / 32;  // 24
  LOADT();
  STORET();
  LOADT();
  __syncthreads();

  for (int t = 0; t < NK; ++t) {
    half8 af[4];
    #pragma unroll
    for (int mi = 0; mi < 4; mi++) {
      int r = (wm << 6) + (mi << 4) + fr;
      af[mi] = *(half8*)(AsB + r * 80 + (((hi ^ (r >> 2)) & 3) << 4));
    }
    #pragma unroll
    for (int ni = 0; ni < 8; ni++) {
      int n = (wn << 7) + (ni << 4) + fr;
      half8 bf_ = *(half8*)(BsB + n * 80 + (((hi ^ (n >> 2)) & 3) << 4));
      #pragma unroll
      for (int mi = 0; mi < 4; mi++)
        acc[mi][ni] = __builtin_amdgcn_mfma_f32_16x16x32_f16(af[mi], bf_, acc[mi][ni], 0, 0, 0);
    }
    __syncthreads();
    if (t + 1 < NK) {
      STORET();
      if (t + 2 < NK) LOADT();
      __syncthreads();
    }
  }

  #pragma unroll
  for (int mi = 0; mi < 4; mi++) {
    #pragma unroll
    for (int r = 0; r < 4; r++) {
      int rr = (wm << 6) + (mi << 4) + (hi << 2) + r;
      if (rr < ne) {
        float w = row_w[r0 + rr];
        int t = row_tok[r0 + rr];
        #pragma unroll
        for (int ni = 0; ni < 8; ni++) {
          int col = n0 + (wn << 7) + (ni << 4) + fr;
          unsafeAtomicAdd(&out[(size_t)t * HID + col], acc[mi][ni][r] * w);
        }
      }
    }
  }
}

// ---------------- launch ----------------
extern "C" void kernel_launch(void* const* d_in, const int* in_sizes, int n_in,
                              void* d_out, int out_size, void* d_ws, size_t ws_size,
                              hipStream_t stream) {
  const float* x = (const float*)d_in[0];
  const float* gw = (const float*)d_in[1];
  const float* wgu = (const float*)d_in[2];
  const float* wd = (const float*)d_in[3];
  float* out = (float*)d_out;
  char* ws = (char*)d_ws;

  int* off = (int*)(ws + 0);                    // 65 ints
  int* topk_id = (int*)(ws + 1024);             // 32 KB
  float* topk_w = (float*)(ws + 1024 + 32768);  // 32 KB
  int* row_tok = (int*)(ws + 1024 + 65536);     // 32 KB
  float* row_w = (float*)(ws + 1024 + 98304);   // 32 KB
  u16* act = (u16*)(ws + 135168);                                  // 12.6 MB
  u16* xh = (u16*)(ws + 135168 + (size_t)TOK * TOPK * IMED * 2);   // 4.2 MB

  router_kernel<<<TOK / 4, 256, 0, stream>>>(x, gw, topk_id, topk_w, xh);
  scan_scatter_kernel<<<1, 256, 0, stream>>>(topk_id, topk_w, off, row_tok, row_w);
  hipMemsetAsync(out, 0, (size_t)TOK * HID * sizeof(float), stream);
  gateup_kernel<<<512, 512, 0, stream>>>(xh, wgu, off, row_tok, act);
  down_kernel<<<512, 512, 0, stream>>>(act, wd, off, row_tok, row_w, out);
}